// Round 9
// baseline (289.565 us; speedup 1.0000x reference)
//
#include <hip/hip_runtime.h>
#include <hip/hip_fp16.h>

// BEV pooling: out[bin, c] = sum over points i with ranks_bev[i]==bin of
//                            depth_flat[ranks_depth[i]] * feat_flat[ranks_feat[i], c]
// ranks_bev is SORTED.
// R7/R8 established the pool loop's cost is insensitive to bytes (fp16),
// 64B granules (192B-padded rows + wd pre-gather), and VMEM instr count —
// the binding resource is the VMEM divergent-gather path itself. This round
// ELIMINATES it: feat is only 4224 rows, so an 8-channel fp16 slice
// (4224 x 16B = 67.5KB) fits in LDS. The random per-point feat read becomes
// ds_read_b32; the only loop VMEM is the COALESCED rf/wd streams.
// Structure: grid = 10 channel-groups x 52 bin-chunks, 512-thr blocks
// (8 waves, 67.5KB LDS -> 2 blocks/CU = 16 waves). Block stages its slice
// (fp32->fp16 cvt inline), then each wave runs bins with the R3-proven loop
// (16 slots x 4 lanes, lane owns 2ch, one-ahead index prefetch). Epilogue:
// 4-level shfl butterfly on 2 floats. Depth pre-gathered (wd, coalesced) —
// an in-loop depth scatter would be re-paid 10x across groups.
// Fallback: exact R3 fp32 path if n_rows > 4224 or workspace insufficient.

#define CHN 80
#define NROWS_MAX 4224
#define NGROUPS 10           // 8 channels per group
#define GCH 8
#define BINS_PER_BLK 784     // ceil(40000/784)=52 chunks
#define SSTRIDE 84           // fallback kernel LDS stride (floats)

struct __align__(16) h8 { __half2 a, b, c, d; };   // 8 halves = 16B

// wd[i] = depth[rd[i]] — full-occupancy random gather at L2 throughput.
__global__ __launch_bounds__(256)
void gather_wd(const float* __restrict__ depth, const int* __restrict__ rd,
               float* __restrict__ wd, int P) {
    int q = blockIdx.x * blockDim.x + threadIdx.x;
    int i4 = q * 4;
    if (i4 + 3 < P) {
        const int4 r = *reinterpret_cast<const int4*>(rd + i4);
        float4 o;
        o.x = depth[r.x]; o.y = depth[r.y]; o.z = depth[r.z]; o.w = depth[r.w];
        *reinterpret_cast<float4*>(wd + i4) = o;
    } else {
        for (int i = i4; i < P; ++i) wd[i] = depth[rd[i]];
    }
}

__global__ __launch_bounds__(256)
void seg_starts_kernel(const int* __restrict__ rb, int* __restrict__ seg,
                       int P, int total_bev) {
    int q = blockIdx.x * blockDim.x + threadIdx.x;   // quad index
    int i4 = q * 4;
    if (i4 >= P) return;
    const int4 v = *reinterpret_cast<const int4*>(rb + i4);
    int prev = (i4 == 0) ? -1 : rb[i4 - 1];
    int cur;
    cur = v.x; for (int b = prev + 1; b <= cur; ++b) seg[b] = i4 + 0; prev = cur;
    cur = v.y; for (int b = prev + 1; b <= cur; ++b) seg[b] = i4 + 1; prev = cur;
    cur = v.z; for (int b = prev + 1; b <= cur; ++b) seg[b] = i4 + 2; prev = cur;
    cur = v.w; for (int b = prev + 1; b <= cur; ++b) seg[b] = i4 + 3; prev = cur;
    if (i4 + 4 >= P) {
        for (int b = prev + 1; b <= total_bev; ++b) seg[b] = P;
    }
}

// One block = one (channel-group g, bin-chunk). 8 waves; wave w owns bins
// chunk_lo + w, +8, +16, ... Lane layout per wave: 16 slots x 4 lanes,
// lane (slot,ll) accumulates channels g*8 + ll*2 + {0,1}.
__global__ __launch_bounds__(512, 4)
void bev_pool_lds(const float* __restrict__ feat,
                  const float* __restrict__ wd,
                  const int* __restrict__ rf,
                  const int* __restrict__ seg,
                  float* __restrict__ out,
                  int total_bev, int n_rows, int nchunks) {
    __shared__ __half lfeat[NROWS_MAX * GCH];        // 4224*8*2B = 67584 B

    const int g     = blockIdx.x / nchunks;          // channel group 0..9
    const int chunk = blockIdx.x - g * nchunks;

    // Stage this group's 8-channel fp16 slice. Row r: 16B at lfeat[r*8],
    // byte offset r*16 (b128-aligned, consecutive threads -> banks spread).
    for (int r = threadIdx.x; r < n_rows; r += 512) {
        const float* src = feat + (size_t)r * CHN + g * GCH;
        const float4 u = *reinterpret_cast<const float4*>(src);
        const float4 v = *reinterpret_cast<const float4*>(src + 4);
        h8 o;
        o.a = __floats2half2_rn(u.x, u.y);
        o.b = __floats2half2_rn(u.z, u.w);
        o.c = __floats2half2_rn(v.x, v.y);
        o.d = __floats2half2_rn(v.z, v.w);
        *reinterpret_cast<h8*>(&lfeat[r * GCH]) = o;
    }
    __syncthreads();

    const int wave = threadIdx.x >> 6;               // 0..7
    const int lane = threadIdx.x & 63;
    const int slot = lane >> 2;                      // 0..15 point slot
    const int ll   = lane & 3;                       // 0..3 channel pair

    const int bin_lo = chunk * BINS_PER_BLK;
    const int bin_hi = min(bin_lo + BINS_PER_BLK, total_bev);

    for (int bin = bin_lo + wave; bin < bin_hi; bin += 8) {   // wave-uniform
        const int lo = seg[bin];
        const int hi = seg[bin + 1];

        float ax = 0.f, ay = 0.f;

        // R3-proven loop shape: per-lane early exit, one-ahead index prefetch.
        // Loop VMEM is coalesced (i spans lo..lo+15 across slots); feat read
        // is ds_read_b32 (bank start (fi*4)%32 spreads over 8 positions).
        int i = lo + slot;
        bool valid = i < hi;
        int fi = 0; float dv = 0.f;
        if (valid) { fi = rf[i]; dv = wd[i]; }
        while (valid) {
            const int ni = i + 16;
            const bool nvalid = ni < hi;
            int nfi = 0; float ndv = 0.f;
            if (nvalid) { nfi = rf[ni]; ndv = wd[ni]; }

            const __half2 hv = *reinterpret_cast<const __half2*>(&lfeat[fi * GCH + ll * 2]);
            const float2 f2 = __half22float2(hv);
            ax += dv * f2.x;
            ay += dv * f2.y;

            i = ni; fi = nfi; dv = ndv; valid = nvalid;
        }

        // Butterfly over the 4 slot bits (lane bits 2..5); 2 floats only.
        #pragma unroll
        for (int ofs = 4; ofs <= 32; ofs <<= 1) {
            ax += __shfl_xor(ax, ofs, 64);
            ay += __shfl_xor(ay, ofs, 64);
        }
        // Lanes 0..3 (slot 0) hold the bin's 8 channels; 4x8B = contiguous 32B.
        if (lane < 4) {
            float2 o; o.x = ax; o.y = ay;
            *reinterpret_cast<float2*>(out + (size_t)bin * CHN + g * GCH + ll * 2) = o;
        }
    }
}

// ---- Fallback: exact R3 fp32 path (in-loop depth gather, LDS transpose) ----
__global__ __launch_bounds__(256)
void bev_pool_f32(const float* __restrict__ depth,
                  const float* __restrict__ feat,
                  const int* __restrict__ rd,
                  const int* __restrict__ rf,
                  const int* __restrict__ seg,
                  float* __restrict__ out,
                  int total_bev) {
    __shared__ float lds_buf[4][16 * SSTRIDE];
    const int wave = threadIdx.x >> 6;
    const int lane = threadIdx.x & 63;
    const int bin = blockIdx.x * 4 + wave;
    if (bin >= total_bev) return;
    const int slot = lane >> 2;
    const int ll   = lane & 3;
    const int lo = seg[bin];
    const int hi = seg[bin + 1];

    float4 a0 = make_float4(0.f, 0.f, 0.f, 0.f);
    float4 a1 = a0, a2 = a0, a3 = a0, a4 = a0;

    int i = lo + slot;
    bool valid = i < hi;
    int di = 0, fi = 0;
    if (valid) { di = rd[i]; fi = rf[i]; }
    while (valid) {
        const int ni = i + 16;
        const bool nvalid = ni < hi;
        int ndi = 0, nfi = 0;
        if (nvalid) { ndi = rd[ni]; nfi = rf[ni]; }
        const float d = depth[di];
        const float4* frow = reinterpret_cast<const float4*>(feat + (size_t)fi * CHN) + ll;
        const float4 f0 = frow[0], f1 = frow[4], f2 = frow[8], f3 = frow[12], f4 = frow[16];
        a0.x += d*f0.x; a0.y += d*f0.y; a0.z += d*f0.z; a0.w += d*f0.w;
        a1.x += d*f1.x; a1.y += d*f1.y; a1.z += d*f1.z; a1.w += d*f1.w;
        a2.x += d*f2.x; a2.y += d*f2.y; a2.z += d*f2.z; a2.w += d*f2.w;
        a3.x += d*f3.x; a3.y += d*f3.y; a3.z += d*f3.z; a3.w += d*f3.w;
        a4.x += d*f4.x; a4.y += d*f4.y; a4.z += d*f4.z; a4.w += d*f4.w;
        i = ni; di = ndi; fi = nfi; valid = nvalid;
    }
    {
        float* wb = &lds_buf[wave][slot * SSTRIDE + 4 * ll];
        *reinterpret_cast<float4*>(wb +  0) = a0;
        *reinterpret_cast<float4*>(wb + 16) = a1;
        *reinterpret_cast<float4*>(wb + 32) = a2;
        *reinterpret_cast<float4*>(wb + 48) = a3;
        *reinterpret_cast<float4*>(wb + 64) = a4;
    }
    const int g = lane >> 5;
    const int c = lane & 31;
    float4 r = make_float4(0.f, 0.f, 0.f, 0.f);
    if (c < 20) {
        const float* rp = &lds_buf[wave][g * 8 * SSTRIDE + c * 4];
        #pragma unroll
        for (int t = 0; t < 8; ++t) {
            const float4 v = *reinterpret_cast<const float4*>(rp + t * SSTRIDE);
            r.x += v.x; r.y += v.y; r.z += v.z; r.w += v.w;
        }
    }
    r.x += __shfl_xor(r.x, 32, 64);
    r.y += __shfl_xor(r.y, 32, 64);
    r.z += __shfl_xor(r.z, 32, 64);
    r.w += __shfl_xor(r.w, 32, 64);
    if (lane < 20) {
        *reinterpret_cast<float4*>(out + (size_t)bin * CHN + lane * 4) = r;
    }
}

extern "C" void kernel_launch(void* const* d_in, const int* in_sizes, int n_in,
                              void* d_out, int out_size, void* d_ws, size_t ws_size,
                              hipStream_t stream) {
    const float* depth = (const float*)d_in[0];
    const float* feat  = (const float*)d_in[1];
    const int*   rd    = (const int*)d_in[2];
    const int*   rf    = (const int*)d_in[3];
    const int*   rb    = (const int*)d_in[4];
    // d_in[5], d_in[6] (interval_starts/lengths) unused per reference; d_in[7] scalar total_bev.
    float* out = (float*)d_out;

    const int P = in_sizes[2];
    const int feat_elems = in_sizes[1];          // n_rows * 80 floats
    const int n_rows = feat_elems / CHN;
    const int total_bev = out_size / CHN;        // 40000

    // Workspace: [seg: (total_bev+1) ints][align 256][wd: P floats]
    int* seg = (int*)d_ws;
    const size_t seg_bytes = ((size_t)(total_bev + 1) * 4 + 255) & ~(size_t)255;
    const size_t need = seg_bytes + (size_t)P * 4;
    float* wd = (float*)((char*)d_ws + seg_bytes);

    const bool lds_ok = (feat_elems % CHN) == 0 && n_rows <= NROWS_MAX &&
                        ws_size >= need;

    const int quads = (P + 3) / 4;
    if (lds_ok) {
        gather_wd<<<(quads + 255) / 256, 256, 0, stream>>>(depth, rd, wd, P);
        seg_starts_kernel<<<(quads + 255) / 256, 256, 0, stream>>>(rb, seg, P, total_bev);
        const int nchunks = (total_bev + BINS_PER_BLK - 1) / BINS_PER_BLK;
        bev_pool_lds<<<NGROUPS * nchunks, 512, 0, stream>>>(
            feat, wd, rf, seg, out, total_bev, n_rows, nchunks);
    } else {
        seg_starts_kernel<<<(quads + 255) / 256, 256, 0, stream>>>(rb, seg, P, total_bev);
        bev_pool_f32<<<(total_bev + 3) / 4, 256, 0, stream>>>(
            depth, feat, rd, rf, seg, out, total_bev);
    }
}

// Round 10
// 110.678 us; speedup vs baseline: 2.6163x; 2.6163x over previous
//
#include <hip/hip_runtime.h>
#include <hip/hip_fp16.h>

// BEV pooling: out[bin, c] = sum over points i with ranks_bev[i]==bin of
//                            depth_flat[ranks_depth[i]] * feat_flat[ranks_feat[i], c]
// ranks_bev is SORTED.
// Cost model (fits R3/R7/R8/R9): pool time ~= unique L1-miss 64B granules
// per wave-iter x ~3cy per granule per CU (shared TCP miss path).
//   fp32: 80 feat + 16 depth + 2 idx = 98 -> 45us (R3)
//   fp16 unpadded: 66 misses + 32 straddle hits -> 34us (R7)
//   fp16 192B-padded + wd: 50 misses -> ~23us, but gather_wd re-pays the
//     depth scatter (+7us) -> net flat (R8)
//   LDS-staged channel groups: 6x worse (R9 — 1 blk/CU, 10x loop replication)
// THIS ROUND (mode 1): 192B-padded fp16 rows (3 aligned granules/row -> 48
// clean misses) + in-loop depth gather (16) + idx (2) = 66 misses and NO
// gather_wd kernel. Expected pool ~30us; floor of this structure is ~4
// misses/point = ~30us.
// Phases: 0) pack_feat_f16 (192B rows)  1) seg lower_bound
//   2) ONE WAVE PER BIN, 16 slots x 4 lanes, R3-proven loop (per-lane early
//      exit + one-ahead index prefetch). Epilogue: LDS transpose-reduce.
// Fallback: exact R3 fp32 path if rows malformed or workspace too small.

#define CHN 80
#define SSTRIDE 84    // floats per slot row in LDS: 80 + 4 pad (16B-aligned)
#define ROWB 192      // padded fp16 feat row bytes (96 halves, 80 used)

struct __align__(8)  h4 { __half2 a, b; };          // 4 halves
struct __align__(16) h8 { __half2 a, b, c, d; };    // 8 halves

// featp row j (192B): halves 0..79 = fp16(feat row j), 80..95 = zero pad.
__global__ __launch_bounds__(256)
void pack_feat_f16(const float* __restrict__ feat, __half* __restrict__ featp,
                   int n_chunks /* n_rows * 24 (192B/8B chunks per row) */) {
    int q = blockIdx.x * blockDim.x + threadIdx.x;
    if (q >= n_chunks) return;
    const int j = q / 24;          // feat row
    const int c = q - j * 24;      // 8B chunk within padded row
    h4 o;
    if (c < 20) {
        const float4 v = *reinterpret_cast<const float4*>(feat + (size_t)j * CHN + c * 4);
        o.a = __floats2half2_rn(v.x, v.y);
        o.b = __floats2half2_rn(v.z, v.w);
    } else {
        o.a = __floats2half2_rn(0.f, 0.f);
        o.b = o.a;
    }
    *reinterpret_cast<h4*>(reinterpret_cast<char*>(featp) + (size_t)j * ROWB + c * 8) = o;
}

__global__ __launch_bounds__(256)
void seg_starts_kernel(const int* __restrict__ rb, int* __restrict__ seg,
                       int P, int total_bev) {
    int q = blockIdx.x * blockDim.x + threadIdx.x;   // quad index
    int i4 = q * 4;
    if (i4 >= P) return;
    const int4 v = *reinterpret_cast<const int4*>(rb + i4);
    int prev = (i4 == 0) ? -1 : rb[i4 - 1];
    int cur;
    cur = v.x; for (int b = prev + 1; b <= cur; ++b) seg[b] = i4 + 0; prev = cur;
    cur = v.y; for (int b = prev + 1; b <= cur; ++b) seg[b] = i4 + 1; prev = cur;
    cur = v.z; for (int b = prev + 1; b <= cur; ++b) seg[b] = i4 + 2; prev = cur;
    cur = v.w; for (int b = prev + 1; b <= cur; ++b) seg[b] = i4 + 3; prev = cur;
    if (i4 + 4 >= P) {
        for (int b = prev + 1; b <= total_bev; ++b) seg[b] = P;
    }
}

// MODE: 0 = fp32 feat (exact R3 path), 1 = packed fp16 feat. Both gather
// depth in-loop.
template <int MODE>
__global__ __launch_bounds__(256)
void bev_pool_kernel(const float* __restrict__ depth,
                     const float* __restrict__ feat,
                     const __half* __restrict__ featp,
                     const int* __restrict__ rd,
                     const int* __restrict__ rf,
                     const int* __restrict__ seg,
                     float* __restrict__ out,
                     int total_bev) {
    __shared__ float lds_buf[4][16 * SSTRIDE];       // per-wave-private 16x84 floats

    const int wave = threadIdx.x >> 6;               // 4 waves per block
    const int lane = threadIdx.x & 63;
    const int bin = blockIdx.x * 4 + wave;
    if (bin >= total_bev) return;

    const int slot = lane >> 2;                      // 0..15 point slot
    const int ll   = lane & 3;                       // 0..3 channel sub-lane

    const int lo = seg[bin];
    const int hi = seg[bin + 1];

    float4 a0 = make_float4(0.f, 0.f, 0.f, 0.f);
    float4 a1 = a0, a2 = a0, a3 = a0, a4 = a0;

    // R3-proven loop: per-lane early exit, one-ahead index prefetch.
    int i = lo + slot;
    bool valid = i < hi;
    int di = 0, fi = 0;
    if (valid) { di = rd[i]; fi = rf[i]; }
    while (valid) {
        const int ni = i + 16;
        const bool nvalid = ni < hi;
        int ndi = 0, nfi = 0;
        if (nvalid) { ndi = rd[ni]; nfi = rf[ni]; }

        const float d = depth[di];
        if constexpr (MODE == 1) {
            // Padded row: 3 aligned granules. Lane ll owns chunks
            // {2ll, 2ll+1, 8+2ll, 9+2ll, 16+ll} (chunk = 4 channels).
            const char* rowp = reinterpret_cast<const char*>(featp) + (size_t)fi * ROWB;
            const h8 u0 = *reinterpret_cast<const h8*>(rowp + (ll << 4));        // ch 8ll..+7
            const h8 u1 = *reinterpret_cast<const h8*>(rowp + 64 + (ll << 4));   // ch 32+8ll..+7
            const h4 u2 = *reinterpret_cast<const h4*>(rowp + 128 + (ll << 3));  // ch 64+4ll..+3
            float2 p, q;
            p = __half22float2(u0.a); q = __half22float2(u0.b);
            a0.x += d*p.x; a0.y += d*p.y; a0.z += d*q.x; a0.w += d*q.y;
            p = __half22float2(u0.c); q = __half22float2(u0.d);
            a1.x += d*p.x; a1.y += d*p.y; a1.z += d*q.x; a1.w += d*q.y;
            p = __half22float2(u1.a); q = __half22float2(u1.b);
            a2.x += d*p.x; a2.y += d*p.y; a2.z += d*q.x; a2.w += d*q.y;
            p = __half22float2(u1.c); q = __half22float2(u1.d);
            a3.x += d*p.x; a3.y += d*p.y; a3.z += d*q.x; a3.w += d*q.y;
            p = __half22float2(u2.a); q = __half22float2(u2.b);
            a4.x += d*p.x; a4.y += d*p.y; a4.z += d*q.x; a4.w += d*q.y;
        } else {
            const float4* frow = reinterpret_cast<const float4*>(feat + (size_t)fi * CHN) + ll;
            const float4 f0 = frow[0];     // chunk ll
            const float4 f1 = frow[4];     // chunk ll+4
            const float4 f2 = frow[8];
            const float4 f3 = frow[12];
            const float4 f4 = frow[16];
            a0.x += d * f0.x; a0.y += d * f0.y; a0.z += d * f0.z; a0.w += d * f0.w;
            a1.x += d * f1.x; a1.y += d * f1.y; a1.z += d * f1.z; a1.w += d * f1.w;
            a2.x += d * f2.x; a2.y += d * f2.y; a2.z += d * f2.z; a2.w += d * f2.w;
            a3.x += d * f3.x; a3.y += d * f3.y; a3.z += d * f3.z; a3.w += d * f3.w;
            a4.x += d * f4.x; a4.y += d * f4.y; a4.z += d * f4.z; a4.w += d * f4.w;
        }

        i = ni; di = ndi; fi = nfi; valid = nvalid;
    }

    // ---- Epilogue: LDS transpose-reduce (R3-proven); write offsets match
    // the mode's chunk ownership. All offsets 16B-aligned (SSTRIDE*4B=336).
    {
        float* wb = &lds_buf[wave][slot * SSTRIDE];
        if constexpr (MODE == 1) {
            *reinterpret_cast<float4*>(wb + 8 * ll)      = a0;   // chunk 2ll
            *reinterpret_cast<float4*>(wb + 8 * ll + 4)  = a1;   // chunk 2ll+1
            *reinterpret_cast<float4*>(wb + 32 + 8 * ll) = a2;   // chunk 8+2ll
            *reinterpret_cast<float4*>(wb + 36 + 8 * ll) = a3;   // chunk 9+2ll
            *reinterpret_cast<float4*>(wb + 64 + 4 * ll) = a4;   // chunk 16+ll
        } else {
            *reinterpret_cast<float4*>(wb + 4 * ll)      = a0;   // chunk ll
            *reinterpret_cast<float4*>(wb + 4 * ll + 16) = a1;   // chunk ll+4
            *reinterpret_cast<float4*>(wb + 4 * ll + 32) = a2;   // chunk ll+8
            *reinterpret_cast<float4*>(wb + 4 * ll + 48) = a3;   // chunk ll+12
            *reinterpret_cast<float4*>(wb + 4 * ll + 64) = a4;   // chunk ll+16
        }
    }
    // Read: group g = lane>>5 sums slots g*8..g*8+7 of chunk c = lane&31
    // (active only for c < 20). Same-wave RAW: LDS ops retire in program
    // order within a wave; region is wave-private so no __syncthreads.
    const int g = lane >> 5;
    const int c = lane & 31;
    float4 r = make_float4(0.f, 0.f, 0.f, 0.f);
    if (c < 20) {
        const float* rp = &lds_buf[wave][g * 8 * SSTRIDE + c * 4];
        #pragma unroll
        for (int t = 0; t < 8; ++t) {
            const float4 v = *reinterpret_cast<const float4*>(rp + t * SSTRIDE);
            r.x += v.x; r.y += v.y; r.z += v.z; r.w += v.w;
        }
    }
    // Merge the two slot-halves: lanes 0..19 get lanes 32..51's partial.
    // Must run at top level (both groups active in the shfl).
    r.x += __shfl_xor(r.x, 32, 64);
    r.y += __shfl_xor(r.y, 32, 64);
    r.z += __shfl_xor(r.z, 32, 64);
    r.w += __shfl_xor(r.w, 32, 64);

    if (lane < 20) {
        *reinterpret_cast<float4*>(out + (size_t)bin * CHN + lane * 4) = r;
    }
}

extern "C" void kernel_launch(void* const* d_in, const int* in_sizes, int n_in,
                              void* d_out, int out_size, void* d_ws, size_t ws_size,
                              hipStream_t stream) {
    const float* depth = (const float*)d_in[0];
    const float* feat  = (const float*)d_in[1];
    const int*   rd    = (const int*)d_in[2];
    const int*   rf    = (const int*)d_in[3];
    const int*   rb    = (const int*)d_in[4];
    // d_in[5], d_in[6] (interval_starts/lengths) unused per reference; d_in[7] scalar total_bev.
    float* out = (float*)d_out;

    const int P = in_sizes[2];
    const int feat_elems = in_sizes[1];          // n_rows * 80 floats
    const int n_rows = feat_elems / CHN;         // 4224
    const int total_bev = out_size / CHN;        // 40000

    // Workspace layout: [seg: (total_bev+1) ints][align 256][featp 192B rows]
    int* seg = (int*)d_ws;
    const size_t seg_bytes   = ((size_t)(total_bev + 1) * 4 + 255) & ~(size_t)255;
    const size_t featp_bytes = (size_t)n_rows * ROWB;
    const size_t need = seg_bytes + featp_bytes;
    __half* featp = (__half*)((char*)d_ws + seg_bytes);

    const bool rows_ok = (feat_elems % CHN) == 0;
    const int mode = (rows_ok && ws_size >= need) ? 1 : 0;

    const int quads = (P + 3) / 4;
    if (mode == 1) {
        const int n_chunks = n_rows * 24;
        pack_feat_f16<<<(n_chunks + 255) / 256, 256, 0, stream>>>(feat, featp, n_chunks);
    }
    seg_starts_kernel<<<(quads + 255) / 256, 256, 0, stream>>>(rb, seg, P, total_bev);

    const int grid = (total_bev + 3) / 4;
    if (mode == 1) {
        bev_pool_kernel<1><<<grid, 256, 0, stream>>>(depth, feat, featp, rd, rf, seg, out, total_bev);
    } else {
        bev_pool_kernel<0><<<grid, 256, 0, stream>>>(depth, feat, featp, rd, rf, seg, out, total_bev);
    }
}

// Round 11
// 108.495 us; speedup vs baseline: 2.6689x; 1.0201x over previous
//
#include <hip/hip_runtime.h>
#include <hip/hip_fp16.h>

// BEV pooling: out[bin, c] = sum over points i with ranks_bev[i]==bin of
//                            depth_flat[ranks_depth[i]] * feat_flat[ranks_feat[i], c]
// ranks_bev is SORTED.
// Cost model (fits R3/R7/R8/R9/R10): pool time ~= unique L1-miss 64B
// granules per wave-iter x ~3cy per granule per CU (TCP miss path).
//   fp32: 98 -> 45us (R3) | fp16 straddled: 66+32 hits -> 34us (R7)
//   fp16 padded + wd: 50 + gather_wd re-pays depth misses -> net loss (R8)
//   fp16 192B-padded, in-loop depth: 66 -> ~30us (R10, best: 110.7 total)
// All per-point granule terms are at their floor (feat 3 = ceil(160/64),
// depth 1, idx coalesced; fp8 would cut feat to 2 but est. absmax ~0.18
// vs passing 0.0625 — rejected). Remaining lever: LAUNCH COUNT.
// THIS ROUND: fuse pack_feat_f16 + seg_starts into ONE prep kernel
// (block-range split, no inter-dependency) -> 2 launches total, saving ~3-4us
// of launch overhead. Pool kernel byte-identical to R10's mode 1.
// Fallback: exact R3 fp32 path if rows malformed or workspace too small.

#define CHN 80
#define SSTRIDE 84    // floats per slot row in LDS: 80 + 4 pad (16B-aligned)
#define ROWB 192      // padded fp16 feat row bytes (96 halves, 80 used)

struct __align__(8)  h4 { __half2 a, b; };          // 4 halves
struct __align__(16) h8 { __half2 a, b, c, d; };    // 8 halves

// Fused prep: blocks [0, pack_blocks) pack feat -> 192B fp16 rows;
// blocks [pack_blocks, ...) compute seg[] lower bounds. Independent work.
__global__ __launch_bounds__(256)
void prep_kernel(const float* __restrict__ feat, __half* __restrict__ featp,
                 int n_chunks, int pack_blocks,
                 const int* __restrict__ rb, int* __restrict__ seg,
                 int P, int total_bev) {
    if ((int)blockIdx.x < pack_blocks) {
        // ---- pack: featp row j (192B): halves 0..79 = fp16(row j), rest 0.
        const int q = blockIdx.x * blockDim.x + threadIdx.x;
        if (q >= n_chunks) return;
        const int j = q / 24;          // feat row
        const int c = q - j * 24;      // 8B chunk within padded row
        h4 o;
        if (c < 20) {
            const float4 v = *reinterpret_cast<const float4*>(feat + (size_t)j * CHN + c * 4);
            o.a = __floats2half2_rn(v.x, v.y);
            o.b = __floats2half2_rn(v.z, v.w);
        } else {
            o.a = __floats2half2_rn(0.f, 0.f);
            o.b = o.a;
        }
        *reinterpret_cast<h4*>(reinterpret_cast<char*>(featp) + (size_t)j * ROWB + c * 8) = o;
    } else {
        // ---- seg: vectorized lower_bound boundary detection (int4).
        const int q = (blockIdx.x - pack_blocks) * blockDim.x + threadIdx.x;
        const int i4 = q * 4;
        if (i4 >= P) return;
        const int4 v = *reinterpret_cast<const int4*>(rb + i4);
        int prev = (i4 == 0) ? -1 : rb[i4 - 1];
        int cur;
        cur = v.x; for (int b = prev + 1; b <= cur; ++b) seg[b] = i4 + 0; prev = cur;
        cur = v.y; for (int b = prev + 1; b <= cur; ++b) seg[b] = i4 + 1; prev = cur;
        cur = v.z; for (int b = prev + 1; b <= cur; ++b) seg[b] = i4 + 2; prev = cur;
        cur = v.w; for (int b = prev + 1; b <= cur; ++b) seg[b] = i4 + 3; prev = cur;
        if (i4 + 4 >= P) {
            for (int b = prev + 1; b <= total_bev; ++b) seg[b] = P;
        }
    }
}

// Standalone seg kernel for the fp32 fallback path.
__global__ __launch_bounds__(256)
void seg_starts_kernel(const int* __restrict__ rb, int* __restrict__ seg,
                       int P, int total_bev) {
    int q = blockIdx.x * blockDim.x + threadIdx.x;
    int i4 = q * 4;
    if (i4 >= P) return;
    const int4 v = *reinterpret_cast<const int4*>(rb + i4);
    int prev = (i4 == 0) ? -1 : rb[i4 - 1];
    int cur;
    cur = v.x; for (int b = prev + 1; b <= cur; ++b) seg[b] = i4 + 0; prev = cur;
    cur = v.y; for (int b = prev + 1; b <= cur; ++b) seg[b] = i4 + 1; prev = cur;
    cur = v.z; for (int b = prev + 1; b <= cur; ++b) seg[b] = i4 + 2; prev = cur;
    cur = v.w; for (int b = prev + 1; b <= cur; ++b) seg[b] = i4 + 3; prev = cur;
    if (i4 + 4 >= P) {
        for (int b = prev + 1; b <= total_bev; ++b) seg[b] = P;
    }
}

// MODE: 0 = fp32 feat (exact R3 path), 1 = packed fp16 feat. Both gather
// depth in-loop.
template <int MODE>
__global__ __launch_bounds__(256)
void bev_pool_kernel(const float* __restrict__ depth,
                     const float* __restrict__ feat,
                     const __half* __restrict__ featp,
                     const int* __restrict__ rd,
                     const int* __restrict__ rf,
                     const int* __restrict__ seg,
                     float* __restrict__ out,
                     int total_bev) {
    __shared__ float lds_buf[4][16 * SSTRIDE];       // per-wave-private 16x84 floats

    const int wave = threadIdx.x >> 6;               // 4 waves per block
    const int lane = threadIdx.x & 63;
    const int bin = blockIdx.x * 4 + wave;
    if (bin >= total_bev) return;

    const int slot = lane >> 2;                      // 0..15 point slot
    const int ll   = lane & 3;                       // 0..3 channel sub-lane

    const int lo = seg[bin];
    const int hi = seg[bin + 1];

    float4 a0 = make_float4(0.f, 0.f, 0.f, 0.f);
    float4 a1 = a0, a2 = a0, a3 = a0, a4 = a0;

    // R3-proven loop: per-lane early exit, one-ahead index prefetch.
    int i = lo + slot;
    bool valid = i < hi;
    int di = 0, fi = 0;
    if (valid) { di = rd[i]; fi = rf[i]; }
    while (valid) {
        const int ni = i + 16;
        const bool nvalid = ni < hi;
        int ndi = 0, nfi = 0;
        if (nvalid) { ndi = rd[ni]; nfi = rf[ni]; }

        const float d = depth[di];
        if constexpr (MODE == 1) {
            // Padded row: 3 aligned granules. Lane ll owns chunks
            // {2ll, 2ll+1, 8+2ll, 9+2ll, 16+ll} (chunk = 4 channels).
            const char* rowp = reinterpret_cast<const char*>(featp) + (size_t)fi * ROWB;
            const h8 u0 = *reinterpret_cast<const h8*>(rowp + (ll << 4));        // ch 8ll..+7
            const h8 u1 = *reinterpret_cast<const h8*>(rowp + 64 + (ll << 4));   // ch 32+8ll..+7
            const h4 u2 = *reinterpret_cast<const h4*>(rowp + 128 + (ll << 3));  // ch 64+4ll..+3
            float2 p, q;
            p = __half22float2(u0.a); q = __half22float2(u0.b);
            a0.x += d*p.x; a0.y += d*p.y; a0.z += d*q.x; a0.w += d*q.y;
            p = __half22float2(u0.c); q = __half22float2(u0.d);
            a1.x += d*p.x; a1.y += d*p.y; a1.z += d*q.x; a1.w += d*q.y;
            p = __half22float2(u1.a); q = __half22float2(u1.b);
            a2.x += d*p.x; a2.y += d*p.y; a2.z += d*q.x; a2.w += d*q.y;
            p = __half22float2(u1.c); q = __half22float2(u1.d);
            a3.x += d*p.x; a3.y += d*p.y; a3.z += d*q.x; a3.w += d*q.y;
            p = __half22float2(u2.a); q = __half22float2(u2.b);
            a4.x += d*p.x; a4.y += d*p.y; a4.z += d*q.x; a4.w += d*q.y;
        } else {
            const float4* frow = reinterpret_cast<const float4*>(feat + (size_t)fi * CHN) + ll;
            const float4 f0 = frow[0];     // chunk ll
            const float4 f1 = frow[4];     // chunk ll+4
            const float4 f2 = frow[8];
            const float4 f3 = frow[12];
            const float4 f4 = frow[16];
            a0.x += d * f0.x; a0.y += d * f0.y; a0.z += d * f0.z; a0.w += d * f0.w;
            a1.x += d * f1.x; a1.y += d * f1.y; a1.z += d * f1.z; a1.w += d * f1.w;
            a2.x += d * f2.x; a2.y += d * f2.y; a2.z += d * f2.z; a2.w += d * f2.w;
            a3.x += d * f3.x; a3.y += d * f3.y; a3.z += d * f3.z; a3.w += d * f3.w;
            a4.x += d * f4.x; a4.y += d * f4.y; a4.z += d * f4.z; a4.w += d * f4.w;
        }

        i = ni; di = ndi; fi = nfi; valid = nvalid;
    }

    // ---- Epilogue: LDS transpose-reduce (R3-proven); write offsets match
    // the mode's chunk ownership. All offsets 16B-aligned (SSTRIDE*4B=336).
    {
        float* wb = &lds_buf[wave][slot * SSTRIDE];
        if constexpr (MODE == 1) {
            *reinterpret_cast<float4*>(wb + 8 * ll)      = a0;   // chunk 2ll
            *reinterpret_cast<float4*>(wb + 8 * ll + 4)  = a1;   // chunk 2ll+1
            *reinterpret_cast<float4*>(wb + 32 + 8 * ll) = a2;   // chunk 8+2ll
            *reinterpret_cast<float4*>(wb + 36 + 8 * ll) = a3;   // chunk 9+2ll
            *reinterpret_cast<float4*>(wb + 64 + 4 * ll) = a4;   // chunk 16+ll
        } else {
            *reinterpret_cast<float4*>(wb + 4 * ll)      = a0;   // chunk ll
            *reinterpret_cast<float4*>(wb + 4 * ll + 16) = a1;   // chunk ll+4
            *reinterpret_cast<float4*>(wb + 4 * ll + 32) = a2;   // chunk ll+8
            *reinterpret_cast<float4*>(wb + 4 * ll + 48) = a3;   // chunk ll+12
            *reinterpret_cast<float4*>(wb + 4 * ll + 64) = a4;   // chunk ll+16
        }
    }
    // Read: group g = lane>>5 sums slots g*8..g*8+7 of chunk c = lane&31
    // (active only for c < 20). Same-wave RAW: LDS ops retire in program
    // order within a wave; region is wave-private so no __syncthreads.
    const int g = lane >> 5;
    const int c = lane & 31;
    float4 r = make_float4(0.f, 0.f, 0.f, 0.f);
    if (c < 20) {
        const float* rp = &lds_buf[wave][g * 8 * SSTRIDE + c * 4];
        #pragma unroll
        for (int t = 0; t < 8; ++t) {
            const float4 v = *reinterpret_cast<const float4*>(rp + t * SSTRIDE);
            r.x += v.x; r.y += v.y; r.z += v.z; r.w += v.w;
        }
    }
    // Merge the two slot-halves: lanes 0..19 get lanes 32..51's partial.
    // Must run at top level (both groups active in the shfl).
    r.x += __shfl_xor(r.x, 32, 64);
    r.y += __shfl_xor(r.y, 32, 64);
    r.z += __shfl_xor(r.z, 32, 64);
    r.w += __shfl_xor(r.w, 32, 64);

    if (lane < 20) {
        *reinterpret_cast<float4*>(out + (size_t)bin * CHN + lane * 4) = r;
    }
}

extern "C" void kernel_launch(void* const* d_in, const int* in_sizes, int n_in,
                              void* d_out, int out_size, void* d_ws, size_t ws_size,
                              hipStream_t stream) {
    const float* depth = (const float*)d_in[0];
    const float* feat  = (const float*)d_in[1];
    const int*   rd    = (const int*)d_in[2];
    const int*   rf    = (const int*)d_in[3];
    const int*   rb    = (const int*)d_in[4];
    // d_in[5], d_in[6] (interval_starts/lengths) unused per reference; d_in[7] scalar total_bev.
    float* out = (float*)d_out;

    const int P = in_sizes[2];
    const int feat_elems = in_sizes[1];          // n_rows * 80 floats
    const int n_rows = feat_elems / CHN;         // 4224
    const int total_bev = out_size / CHN;        // 40000

    // Workspace layout: [seg: (total_bev+1) ints][align 256][featp 192B rows]
    int* seg = (int*)d_ws;
    const size_t seg_bytes   = ((size_t)(total_bev + 1) * 4 + 255) & ~(size_t)255;
    const size_t featp_bytes = (size_t)n_rows * ROWB;
    const size_t need = seg_bytes + featp_bytes;
    __half* featp = (__half*)((char*)d_ws + seg_bytes);

    const bool rows_ok = (feat_elems % CHN) == 0;
    const int mode = (rows_ok && ws_size >= need) ? 1 : 0;

    const int quads = (P + 3) / 4;
    const int seg_blocks = (quads + 255) / 256;
    if (mode == 1) {
        const int n_chunks = n_rows * 24;
        const int pack_blocks = (n_chunks + 255) / 256;
        prep_kernel<<<pack_blocks + seg_blocks, 256, 0, stream>>>(
            feat, featp, n_chunks, pack_blocks, rb, seg, P, total_bev);
    } else {
        seg_starts_kernel<<<seg_blocks, 256, 0, stream>>>(rb, seg, P, total_bev);
    }

    const int grid = (total_bev + 3) / 4;
    if (mode == 1) {
        bev_pool_kernel<1><<<grid, 256, 0, stream>>>(depth, feat, featp, rd, rf, seg, out, total_bev);
    } else {
        bev_pool_kernel<0><<<grid, 256, 0, stream>>>(depth, feat, featp, rd, rf, seg, out, total_bev);
    }
}